// Round 1
// baseline (226.654 us; speedup 1.0000x reference)
//
#include <hip/hip_runtime.h>

// GAT layer: B=8, N=2048, Fin=Fout=64
// K1: Wh = h@W (MFMA bf16, stored transposed bf16 WhT[b][o][n]); s,t fp32-exact via Wa1=W@a1.
// K2: flash-style masked softmax + P@Wh (MFMA bf16), adj streamed once (134 MB = HBM floor).

#define NB 8
#define NN 2048
#define NF 64
#define ALPHA 0.2f

typedef __attribute__((ext_vector_type(8))) short  short8;
typedef __attribute__((ext_vector_type(4))) float  f32x4;

static __device__ __forceinline__ unsigned short f2bf(float f) {
    unsigned u = __builtin_bit_cast(unsigned, f);
    u += 0x7fffu + ((u >> 16) & 1u);   // round-to-nearest-even
    return (unsigned short)(u >> 16);
}

// ---------------- K1: Wh (bf16, transposed) + s,t (fp32) ----------------
// grid 256 blocks x 256 thr; block = 64 rows (4 waves x 16-row MFMA tile)
__global__ __launch_bounds__(256) void k1_wh_st(
    const float* __restrict__ h, const float* __restrict__ W,
    const float* __restrict__ a, unsigned short* __restrict__ whT,
    float* __restrict__ sw, float* __restrict__ tw)
{
    __shared__ float W_l[64 * 65];
    __shared__ float wa[128];          // Wa1[64] | Wa2[64]
    __shared__ float tile[4 * 16 * 65];

    const int tid  = threadIdx.x;
    const int lane = tid & 63, wv = tid >> 6;
    const int im   = lane & 15, kq = lane >> 4;

    // stage W -> LDS (padded stride 65)
    #pragma unroll
    for (int k = 0; k < 16; ++k) {
        int e = tid + 256 * k;
        W_l[(e >> 6) * 65 + (e & 63)] = W[e];
    }
    __syncthreads();

    // Wa1[f] = sum_o W[f][o]*a1[o]; Wa2 likewise (threads 0..127)
    if (tid < 128) {
        int f = tid & 63;
        const float* ap = a + (tid >> 6) * 64;
        float acc = 0.f;
        #pragma unroll 8
        for (int o = 0; o < 64; ++o) acc += W_l[f * 65 + o] * ap[o];
        wa[tid] = acc;
    }
    __syncthreads();

    // B fragments: B[k][n] = W[k][nb*16+n], lane: n=im, k=kq*8+u
    short8 bf[4][2];
    #pragma unroll
    for (int nb = 0; nb < 4; ++nb)
        #pragma unroll
        for (int ks = 0; ks < 2; ++ks)
            #pragma unroll
            for (int u = 0; u < 8; ++u)
                bf[nb][ks][u] = (short)f2bf(W_l[(ks * 32 + kq * 8 + u) * 65 + nb * 16 + im]);

    // A fragments: 16 rows of h for this wave
    const int row0 = blockIdx.x * 64 + wv * 16;
    const int bb = row0 >> 11, n_base = row0 & 2047;
    const float* hrow = h + (size_t)(row0 + im) * 64;

    float hv[2][8];
    short8 af[2];
    float sp = 0.f, tp = 0.f;
    #pragma unroll
    for (int ks = 0; ks < 2; ++ks) {
        float4 A = *(const float4*)(hrow + ks * 32 + kq * 8);
        float4 Bv = *(const float4*)(hrow + ks * 32 + kq * 8 + 4);
        hv[ks][0] = A.x;  hv[ks][1] = A.y;  hv[ks][2] = A.z;  hv[ks][3] = A.w;
        hv[ks][4] = Bv.x; hv[ks][5] = Bv.y; hv[ks][6] = Bv.z; hv[ks][7] = Bv.w;
        #pragma unroll
        for (int u = 0; u < 8; ++u) {
            int f = ks * 32 + kq * 8 + u;
            sp += hv[ks][u] * wa[f];
            tp += hv[ks][u] * wa[64 + f];
            af[ks][u] = (short)f2bf(hv[ks][u]);
        }
    }
    // reduce partials across the 4 k-quads (lanes im, im+16, im+32, im+48)
    sp += __shfl_xor(sp, 16, 64); sp += __shfl_xor(sp, 32, 64);
    tp += __shfl_xor(tp, 16, 64); tp += __shfl_xor(tp, 32, 64);
    if (lane < 16) {
        sw[row0 + lane] = sp;
        tw[row0 + lane] = tp;
    }

    f32x4 acc[4] = {{0.f,0.f,0.f,0.f},{0.f,0.f,0.f,0.f},{0.f,0.f,0.f,0.f},{0.f,0.f,0.f,0.f}};
    #pragma unroll
    for (int ks = 0; ks < 2; ++ks)
        #pragma unroll
        for (int nb = 0; nb < 4; ++nb)
            acc[nb] = __builtin_amdgcn_mfma_f32_16x16x32_bf16(af[ks], bf[nb][ks], acc[nb], 0, 0, 0);

    // C layout: i = kq*4 + r, o = nb*16 + im  -> LDS tile, then transposed bf16 store
    #pragma unroll
    for (int nb = 0; nb < 4; ++nb)
        #pragma unroll
        for (int r = 0; r < 4; ++r)
            tile[wv * 1040 + (kq * 4 + r) * 65 + nb * 16 + im] = acc[nb][r];
    __syncthreads();

    #pragma unroll
    for (int k = 0; k < 16; ++k) {
        int o = kq + 4 * k;
        float v = tile[wv * 1040 + im * 65 + o];
        whT[(size_t)(bb * 64 + o) * 2048 + n_base + im] = f2bf(v);
    }
}

// ---------------- K2: masked softmax + P@Wh ----------------
// grid 1024 blocks (b, i0) x 256 thr; waves own contiguous 512-j stripes.
__global__ __launch_bounds__(256, 4) void k2_attn(
    const int* __restrict__ adj, const unsigned short* __restrict__ whT,
    const float* __restrict__ sw, const float* __restrict__ tw,
    float* __restrict__ out)
{
    __shared__ float cpart[4 * 1040];
    __shared__ float zp[64];

    const int tid  = threadIdx.x;
    const int lane = tid & 63, wv = tid >> 6;
    const int im   = lane & 15, kq = lane >> 4;
    const int b    = blockIdx.x >> 7;
    const int i0   = (blockIdx.x & 127) << 4;

    const int j00 = wv * 512 + kq * 8;
    const int*   adj_p = adj + ((size_t)(b * 2048 + i0 + im) * 2048 + j00);
    const float* t_p   = tw + (size_t)b * 2048 + j00;
    const unsigned short* whp0 = whT + ((size_t)(b * 64 +  0 + im) * 2048 + j00);
    const unsigned short* whp1 = whT + ((size_t)(b * 64 + 16 + im) * 2048 + j00);
    const unsigned short* whp2 = whT + ((size_t)(b * 64 + 32 + im) * 2048 + j00);
    const unsigned short* whp3 = whT + ((size_t)(b * 64 + 48 + im) * 2048 + j00);
    const float sl = sw[b * 2048 + i0 + im];

    f32x4 acc0 = {0.f,0.f,0.f,0.f}, acc1 = {0.f,0.f,0.f,0.f};
    f32x4 acc2 = {0.f,0.f,0.f,0.f}, acc3 = {0.f,0.f,0.f,0.f};
    float zs = 0.f;

    int4   ca = *(const int4*)(adj_p),     cb = *(const int4*)(adj_p + 4);
    float4 ta = *(const float4*)(t_p),     tb = *(const float4*)(t_p + 4);

    #pragma unroll 1
    for (int s = 0; s < 16; ++s) {
        // B fragments for this j-step (L2-resident bf16, contiguous 16B)
        short8 w0 = *(const short8*)(const void*)(whp0 + s * 32);
        short8 w1 = *(const short8*)(const void*)(whp1 + s * 32);
        short8 w2 = *(const short8*)(const void*)(whp2 + s * 32);
        short8 w3 = *(const short8*)(const void*)(whp3 + s * 32);

        // prefetch next step's adj + t (HBM latency cover)
        int4 na = {0,0,0,0}, nb_ = {0,0,0,0};
        float4 nta = {0.f,0.f,0.f,0.f}, ntb = {0.f,0.f,0.f,0.f};
        if (s < 15) {
            na  = *(const int4*)(adj_p + (s + 1) * 32);
            nb_ = *(const int4*)(adj_p + (s + 1) * 32 + 4);
            nta = *(const float4*)(t_p + (s + 1) * 32);
            ntb = *(const float4*)(t_p + (s + 1) * 32 + 4);
        }

        // P fragment directly in MFMA A layout: i = im, k = kq*8 + u
        short8 af;
        {
            float tv[8] = {ta.x, ta.y, ta.z, ta.w, tb.x, tb.y, tb.z, tb.w};
            int   av[8] = {ca.x, ca.y, ca.z, ca.w, cb.x, cb.y, cb.z, cb.w};
            #pragma unroll
            for (int u = 0; u < 8; ++u) {
                float e = sl + tv[u];
                e = e > 0.f ? e : ALPHA * e;
                float wgt = (av[u] > 0) ? __expf(e) : 0.f;
                zs += wgt;
                af[u] = (short)f2bf(wgt);
            }
        }

        acc0 = __builtin_amdgcn_mfma_f32_16x16x32_bf16(af, w0, acc0, 0, 0, 0);
        acc1 = __builtin_amdgcn_mfma_f32_16x16x32_bf16(af, w1, acc1, 0, 0, 0);
        acc2 = __builtin_amdgcn_mfma_f32_16x16x32_bf16(af, w2, acc2, 0, 0, 0);
        acc3 = __builtin_amdgcn_mfma_f32_16x16x32_bf16(af, w3, acc3, 0, 0, 0);

        ca = na; cb = nb_; ta = nta; tb = ntb;
    }

    // Z: reduce across the 4 k-quads holding the same i
    zs += __shfl_xor(zs, 16, 64);
    zs += __shfl_xor(zs, 32, 64);
    if (lane < 16) zp[wv * 16 + lane] = zs;

    // per-wave partial C -> LDS (i = kq*4+r, o = nb*16+im)
    #pragma unroll
    for (int r = 0; r < 4; ++r) {
        cpart[wv * 1040 + (kq * 4 + r) * 65 +  0 + im] = acc0[r];
        cpart[wv * 1040 + (kq * 4 + r) * 65 + 16 + im] = acc1[r];
        cpart[wv * 1040 + (kq * 4 + r) * 65 + 32 + im] = acc2[r];
        cpart[wv * 1040 + (kq * 4 + r) * 65 + 48 + im] = acc3[r];
    }
    __syncthreads();

    // cross-wave reduce + softmax normalize + ELU + store
    #pragma unroll
    for (int k = 0; k < 4; ++k) {
        int idx = tid + 256 * k;
        int i = idx >> 6, o = idx & 63;
        float ssum = cpart[0 * 1040 + i * 65 + o] + cpart[1 * 1040 + i * 65 + o]
                   + cpart[2 * 1040 + i * 65 + o] + cpart[3 * 1040 + i * 65 + o];
        float z = zp[i] + zp[16 + i] + zp[32 + i] + zp[48 + i];
        if (z == 0.f) z = 1.f;               // fully-masked row guard (prob ~0)
        float r = ssum / z;
        out[((size_t)(b * 2048 + i0 + i)) * 64 + o] = r > 0.f ? r : expm1f(r);
    }
}

extern "C" void kernel_launch(void* const* d_in, const int* in_sizes, int n_in,
                              void* d_out, int out_size, void* d_ws, size_t ws_size,
                              hipStream_t stream) {
    const float* h   = (const float*)d_in[0];
    const int*   adj = (const int*)d_in[1];
    const float* W   = (const float*)d_in[2];
    const float* a   = (const float*)d_in[3];
    float* out = (float*)d_out;

    unsigned short* whT = (unsigned short*)d_ws;                       // 8*64*2048*2 = 2 MiB
    float* sw = (float*)((char*)d_ws + 2097152);                       // 64 KiB
    float* tw = (float*)((char*)d_ws + 2097152 + 65536);               // 64 KiB

    hipLaunchKernelGGL(k1_wh_st, dim3(256), dim3(256), 0, stream, h, W, a, whT, sw, tw);
    hipLaunchKernelGGL(k2_attn, dim3(1024), dim3(256), 0, stream, adj, whT, sw, tw, out);
}